// Round 1
// baseline (3737.605 us; speedup 1.0000x reference)
//
#include <hip/hip_runtime.h>

#define N_NODES 50000
#define N_EDGES 800000
#define DIM 128
#define NLAYERS 3
#define NCLASSES 6
#define NGRAPHS 64
#define BN_EPS 1e-5f

#define SCAN_BLK 256
#define SCAN_NB ((N_NODES + SCAN_BLK - 1) / SCAN_BLK)  // 196

// ---------------- CSR build ----------------

__global__ void k_count(const int* __restrict__ dst, int* __restrict__ cnt) {
  int e = blockIdx.x * blockDim.x + threadIdx.x;
  if (e < N_EDGES) atomicAdd(&cnt[dst[e]], 1);
}

__global__ void k_scan_a(const int* __restrict__ cnt, int* __restrict__ incl,
                         int* __restrict__ bsum) {
  __shared__ int s[SCAN_BLK];
  int i = blockIdx.x * SCAN_BLK + threadIdx.x;
  int v = (i < N_NODES) ? cnt[i] : 0;
  s[threadIdx.x] = v;
  __syncthreads();
  for (int off = 1; off < SCAN_BLK; off <<= 1) {
    int t = (threadIdx.x >= off) ? s[threadIdx.x - off] : 0;
    __syncthreads();
    s[threadIdx.x] += t;
    __syncthreads();
  }
  if (i < N_NODES) incl[i] = s[threadIdx.x];
  if (threadIdx.x == SCAN_BLK - 1) bsum[blockIdx.x] = s[SCAN_BLK - 1];
}

__global__ void k_scan_b(const int* __restrict__ bsum, int* __restrict__ boff) {
  __shared__ int s[SCAN_BLK];
  int t = threadIdx.x;
  int v = (t < SCAN_NB) ? bsum[t] : 0;
  s[t] = v;
  __syncthreads();
  for (int off = 1; off < SCAN_BLK; off <<= 1) {
    int u = (t >= off) ? s[t - off] : 0;
    __syncthreads();
    s[t] += u;
    __syncthreads();
  }
  boff[t] = s[t] - v;  // exclusive prefix of block sums
}

__global__ void k_scan_c(const int* __restrict__ cnt, const int* __restrict__ incl,
                         const int* __restrict__ boff, int* __restrict__ row_ptr,
                         int* __restrict__ cursor, float* __restrict__ degf) {
  int i = blockIdx.x * SCAN_BLK + threadIdx.x;
  if (i < N_NODES) {
    int ex = incl[i] - cnt[i] + boff[blockIdx.x];
    row_ptr[i] = ex;
    cursor[i] = ex;
    degf[i] = (float)max(cnt[i], 1);
  }
  if (i == 0) row_ptr[N_NODES] = N_EDGES;
}

__global__ void k_fill(const int* __restrict__ src, const int* __restrict__ dst,
                       int* __restrict__ cursor, int* __restrict__ col) {
  int e = blockIdx.x * blockDim.x + threadIdx.x;
  if (e < N_EDGES) {
    int pos = atomicAdd(&cursor[dst[e]], 1);
    col[pos] = src[e];
  }
}

// ---------------- per-layer kernels ----------------

// one wave per node; lane holds 2 features (float2) -> coalesced 512B row reads
__global__ void k_gather(const float* __restrict__ xin, const int* __restrict__ row_ptr,
                         const int* __restrict__ col, const float* __restrict__ degf,
                         float* __restrict__ agg) {
  int wid = threadIdx.x >> 6, lane = threadIdx.x & 63;
  int n = blockIdx.x * 4 + wid;
  if (n >= N_NODES) return;
  int beg = row_ptr[n], end = row_ptr[n + 1];
  const float2* x2 = (const float2*)xin;
  float ax = 0.f, ay = 0.f;
  for (int p = beg; p < end; ++p) {
    float2 v = x2[col[p] * 64 + lane];
    ax += v.x;
    ay += v.y;
  }
  float inv = 1.0f / degf[n];
  ((float2*)agg)[n * 64 + lane] = make_float2(ax * inv, ay * inv);
}

// h[n][j] = bl[j] + agg[n] . Wl[j] + x[n] . Wr[j]
__global__ void k_gemm(const float* __restrict__ agg, const float* __restrict__ xin,
                       const float* __restrict__ Wl, const float* __restrict__ bl,
                       const float* __restrict__ Wr, float* __restrict__ h) {
  int tid = blockIdx.x * blockDim.x + threadIdx.x;
  int n = tid >> 7, j = tid & 127;
  if (n >= N_NODES) return;
  const float4* a4 = (const float4*)(agg + n * DIM);
  const float4* x4 = (const float4*)(xin + n * DIM);
  const float4* l4 = (const float4*)(Wl + j * DIM);
  const float4* r4 = (const float4*)(Wr + j * DIM);
  float acc = bl[j];
#pragma unroll
  for (int k = 0; k < DIM / 4; ++k) {
    float4 a = a4[k], w = l4[k];
    acc += a.x * w.x + a.y * w.y + a.z * w.z + a.w * w.w;
    float4 b = x4[k], u = r4[k];
    acc += b.x * u.x + b.y * u.y + b.z * u.z + b.w * u.w;
  }
  h[n * DIM + j] = acc;
}

__global__ void k_bn_stats(const float* __restrict__ h, float* __restrict__ sums) {
  int j = threadIdx.x;  // 128 threads = 128 features
  float s = 0.f, q = 0.f;
  for (int n = blockIdx.x; n < N_NODES; n += gridDim.x) {
    float v = h[n * DIM + j];
    s += v;
    q += v * v;
  }
  atomicAdd(&sums[j], s);
  atomicAdd(&sums[DIM + j], q);
}

__global__ void k_bn_apply(const float* __restrict__ h, const float* __restrict__ sums,
                           const float* __restrict__ gamma, const float* __restrict__ beta,
                           float* __restrict__ xout) {
  int i = blockIdx.x * blockDim.x + threadIdx.x;
  if (i >= N_NODES * DIM) return;
  int j = i & (DIM - 1);
  float mu = sums[j] * (1.0f / N_NODES);
  float var = sums[DIM + j] * (1.0f / N_NODES) - mu * mu;
  float sc = gamma[j] * rsqrtf(var + BN_EPS);
  float v = (h[i] - mu) * sc + beta[j];
  xout[i] = fmaxf(v, 0.f);
}

// ---------------- pooling + head ----------------

__global__ void k_pool(const float* __restrict__ x, const int* __restrict__ batch,
                       float* __restrict__ pooled, float* __restrict__ gcnt) {
  int i = blockIdx.x * blockDim.x + threadIdx.x;
  if (i >= N_NODES * DIM) return;
  int n = i >> 7, j = i & 127;
  int g = batch[n];
  atomicAdd(&pooled[g * DIM + j], x[i]);
  if (j == 0) atomicAdd(&gcnt[g], 1.0f);
}

__global__ void k_head(const float* __restrict__ pooled, const float* __restrict__ gcnt,
                       const float* __restrict__ W1, const float* __restrict__ b1,
                       const float* __restrict__ W2, const float* __restrict__ b2,
                       float* __restrict__ out) {
  __shared__ float pm[NGRAPHS * DIM];   // 32 KB
  __shared__ float hid[NGRAPHS * 64];   // 16 KB
  for (int i = threadIdx.x; i < NGRAPHS * DIM; i += blockDim.x) {
    int g = i >> 7;
    pm[i] = pooled[i] / fmaxf(gcnt[g], 1.0f);
  }
  __syncthreads();
  for (int i = threadIdx.x; i < NGRAPHS * 64; i += blockDim.x) {
    int g = i >> 6, m = i & 63;
    float acc = b1[m];
    for (int k = 0; k < DIM; ++k) acc += pm[g * DIM + k] * W1[m * DIM + k];
    hid[i] = fmaxf(acc, 0.f);
  }
  __syncthreads();
  for (int i = threadIdx.x; i < NGRAPHS * NCLASSES; i += blockDim.x) {
    int g = i / NCLASSES, c = i % NCLASSES;
    float acc = b2[c];
    for (int m = 0; m < 64; ++m) acc += hid[g * 64 + m] * W2[c * 64 + m];
    out[i] = acc;
  }
}

// ---------------- launch ----------------

extern "C" void kernel_launch(void* const* d_in, const int* in_sizes, int n_in,
                              void* d_out, int out_size, void* d_ws, size_t ws_size,
                              hipStream_t stream) {
  const float* x = (const float*)d_in[0];
  const int* edge = (const int*)d_in[1];
  const int* batch = (const int*)d_in[2];
  const float* Wl = (const float*)d_in[3];
  const float* bl = (const float*)d_in[4];
  const float* Wr = (const float*)d_in[5];
  const float* gamma = (const float*)d_in[6];
  const float* beta = (const float*)d_in[7];
  const float* W1 = (const float*)d_in[8];
  const float* b1 = (const float*)d_in[9];
  const float* W2 = (const float*)d_in[10];
  const float* b2 = (const float*)d_in[11];
  float* out = (float*)d_out;

  const int* src = edge;
  const int* dst = edge + N_EDGES;

  char* p = (char*)d_ws;
  auto alloc = [&](size_t bytes) -> void* {
    void* r = (void*)p;
    p += (bytes + 255) & ~(size_t)255;
    return r;
  };
  int* cnt = (int*)alloc(N_NODES * 4);
  int* incl = (int*)alloc(N_NODES * 4);
  int* bsum = (int*)alloc(SCAN_BLK * 4);
  int* boff = (int*)alloc(SCAN_BLK * 4);
  int* row_ptr = (int*)alloc((N_NODES + 1) * 4);
  int* cursor = (int*)alloc(N_NODES * 4);
  int* col = (int*)alloc(N_EDGES * 4);
  float* degf = (float*)alloc(N_NODES * 4);
  float* x_cur = (float*)alloc((size_t)N_NODES * DIM * 4);
  float* agg = (float*)alloc((size_t)N_NODES * DIM * 4);
  float* hbuf = (float*)alloc((size_t)N_NODES * DIM * 4);
  float* sums = (float*)alloc(2 * DIM * 4);
  float* pooled = (float*)alloc(NGRAPHS * DIM * 4);
  float* gcnt = (float*)alloc(NGRAPHS * 4);

  // ---- CSR build ----
  hipMemsetAsync(cnt, 0, N_NODES * 4, stream);
  k_count<<<(N_EDGES + 255) / 256, 256, 0, stream>>>(dst, cnt);
  k_scan_a<<<SCAN_NB, SCAN_BLK, 0, stream>>>(cnt, incl, bsum);
  k_scan_b<<<1, SCAN_BLK, 0, stream>>>(bsum, boff);
  k_scan_c<<<SCAN_NB, SCAN_BLK, 0, stream>>>(cnt, incl, boff, row_ptr, cursor, degf);
  k_fill<<<(N_EDGES + 255) / 256, 256, 0, stream>>>(src, dst, cursor, col);

  // ---- layers ----
  const float* xin = x;
  for (int l = 0; l < NLAYERS; ++l) {
    k_gather<<<(N_NODES + 3) / 4, 256, 0, stream>>>(xin, row_ptr, col, degf, agg);
    k_gemm<<<(N_NODES * DIM) / 256, 256, 0, stream>>>(
        agg, xin, Wl + (size_t)l * DIM * DIM, bl + (size_t)l * DIM,
        Wr + (size_t)l * DIM * DIM, hbuf);
    hipMemsetAsync(sums, 0, 2 * DIM * 4, stream);
    k_bn_stats<<<512, DIM, 0, stream>>>(hbuf, sums);
    k_bn_apply<<<(N_NODES * DIM + 255) / 256, 256, 0, stream>>>(
        hbuf, sums, gamma + (size_t)l * DIM, beta + (size_t)l * DIM, x_cur);
    xin = x_cur;
  }

  // ---- pool + head ----
  hipMemsetAsync(pooled, 0, NGRAPHS * DIM * 4, stream);
  hipMemsetAsync(gcnt, 0, NGRAPHS * 4, stream);
  k_pool<<<(N_NODES * DIM) / 256, 256, 0, stream>>>(x_cur, batch, pooled, gcnt);
  k_head<<<1, 256, 0, stream>>>(pooled, gcnt, W1, b1, W2, b2, out);
}

// Round 2
// 1153.650 us; speedup vs baseline: 3.2398x; 3.2398x over previous
//
#include <hip/hip_runtime.h>

#define N_NODES 50000
#define N_EDGES 800000
#define DIM 128
#define NLAYERS 3
#define NCLASSES 6
#define NGRAPHS 64
#define BN_EPS 1e-5f

#define SCAN_BLK 256
#define SCAN_NB ((N_NODES + SCAN_BLK - 1) / SCAN_BLK)  // 196

// GEMM tiling
#define TM 128
#define KB 32
#define GEMM_NB ((N_NODES + TM - 1) / TM)  // 391

// ---------------- CSR build ----------------

__global__ void k_count(const int* __restrict__ dst, int* __restrict__ cnt) {
  int e = blockIdx.x * blockDim.x + threadIdx.x;
  if (e < N_EDGES) atomicAdd(&cnt[dst[e]], 1);
}

__global__ void k_scan_a(const int* __restrict__ cnt, int* __restrict__ incl,
                         int* __restrict__ bsum) {
  __shared__ int s[SCAN_BLK];
  int i = blockIdx.x * SCAN_BLK + threadIdx.x;
  int v = (i < N_NODES) ? cnt[i] : 0;
  s[threadIdx.x] = v;
  __syncthreads();
  for (int off = 1; off < SCAN_BLK; off <<= 1) {
    int t = (threadIdx.x >= off) ? s[threadIdx.x - off] : 0;
    __syncthreads();
    s[threadIdx.x] += t;
    __syncthreads();
  }
  if (i < N_NODES) incl[i] = s[threadIdx.x];
  if (threadIdx.x == SCAN_BLK - 1) bsum[blockIdx.x] = s[SCAN_BLK - 1];
}

__global__ void k_scan_b(const int* __restrict__ bsum, int* __restrict__ boff) {
  __shared__ int s[SCAN_BLK];
  int t = threadIdx.x;
  int v = (t < SCAN_NB) ? bsum[t] : 0;
  s[t] = v;
  __syncthreads();
  for (int off = 1; off < SCAN_BLK; off <<= 1) {
    int u = (t >= off) ? s[t - off] : 0;
    __syncthreads();
    s[t] += u;
    __syncthreads();
  }
  boff[t] = s[t] - v;  // exclusive prefix of block sums
}

__global__ void k_scan_c(const int* __restrict__ cnt, const int* __restrict__ incl,
                         const int* __restrict__ boff, int* __restrict__ row_ptr,
                         int* __restrict__ cursor, float* __restrict__ degf) {
  int i = blockIdx.x * SCAN_BLK + threadIdx.x;
  if (i < N_NODES) {
    int ex = incl[i] - cnt[i] + boff[blockIdx.x];
    row_ptr[i] = ex;
    cursor[i] = ex;
    degf[i] = (float)max(cnt[i], 1);
  }
  if (i == 0) row_ptr[N_NODES] = N_EDGES;
}

__global__ void k_fill(const int* __restrict__ src, const int* __restrict__ dst,
                       int* __restrict__ cursor, int* __restrict__ col) {
  int e = blockIdx.x * blockDim.x + threadIdx.x;
  if (e < N_EDGES) {
    int pos = atomicAdd(&cursor[dst[e]], 1);
    col[pos] = src[e];
  }
}

// ---------------- weight pre-transpose ----------------
// Wt[l][k][j]: k<128 -> Wl[l][j][k], k>=128 -> Wr[l][j][k-128]
__global__ void k_wt(const float* __restrict__ Wl, const float* __restrict__ Wr,
                     float* __restrict__ Wt) {
  int i = blockIdx.x * blockDim.x + threadIdx.x;  // over NLAYERS*256*128
  if (i >= NLAYERS * 2 * DIM * DIM) return;
  int j = i & (DIM - 1);
  int k = (i >> 7) & 255;
  int l = i >> 15;
  float v;
  if (k < DIM)
    v = Wl[(size_t)l * DIM * DIM + j * DIM + k];
  else
    v = Wr[(size_t)l * DIM * DIM + j * DIM + (k - DIM)];
  Wt[i] = v;
}

// ---------------- per-layer kernels ----------------

// one wave per node; lane holds 2 features (float2) -> coalesced 512B row reads
__global__ void k_gather(const float* __restrict__ xin, const int* __restrict__ row_ptr,
                         const int* __restrict__ col, const float* __restrict__ degf,
                         float* __restrict__ agg) {
  int wid = threadIdx.x >> 6, lane = threadIdx.x & 63;
  int n = blockIdx.x * 4 + wid;
  if (n >= N_NODES) return;
  int beg = row_ptr[n], end = row_ptr[n + 1];
  const float2* x2 = (const float2*)xin;
  float ax = 0.f, ay = 0.f;
  for (int p = beg; p < end; ++p) {
    float2 v = x2[col[p] * 64 + lane];
    ax += v.x;
    ay += v.y;
  }
  float inv = 1.0f / degf[n];
  ((float2*)agg)[n * 64 + lane] = make_float2(ax * inv, ay * inv);
}

// Tiled SGEMM: h[n][j] = bl[j] + sum_k [agg|x][n][k] * Wt[k][j]
// 128x128 tile per 256-thread block, KB=32, 8x8 register tile.
__global__ __launch_bounds__(256) void k_gemm2(
    const float* __restrict__ agg, const float* __restrict__ xin,
    const float* __restrict__ Wt, const float* __restrict__ bl,
    float* __restrict__ h) {
  __shared__ float As[KB][TM + 1];  // transposed A tile (k-major)
  __shared__ float Bs[KB][DIM];
  int n0 = blockIdx.x * TM;
  int tid = threadIdx.x;
  int tr = tid >> 4;  // 0..15 -> rows 8*tr..
  int tc = tid & 15;  // 0..15 -> cols 8*tc..

  float acc[8][8];
#pragma unroll
  for (int i = 0; i < 8; ++i)
#pragma unroll
    for (int j = 0; j < 8; ++j) acc[i][j] = 0.f;

#pragma unroll 1
  for (int kb = 0; kb < 8; ++kb) {
    const float* Asrc = (kb < 4) ? agg : xin;
    int c0 = (kb & 3) * KB;
    // --- load A tile: 128 rows x 32 cols, transpose into As ---
#pragma unroll
    for (int p = 0; p < 4; ++p) {
      int r = p * 32 + (tid >> 3);
      int rg = n0 + r;
      if (rg > N_NODES - 1) rg = N_NODES - 1;  // clamp (stores are guarded)
      int c4 = (tid & 7) * 4;
      float4 v = *(const float4*)(Asrc + (size_t)rg * DIM + c0 + c4);
      As[c4 + 0][r] = v.x;
      As[c4 + 1][r] = v.y;
      As[c4 + 2][r] = v.z;
      As[c4 + 3][r] = v.w;
    }
    // --- load B tile: 32 rows x 128 cols (straight copy) ---
    {
      int kk = tid >> 3;
      int j0 = (tid & 7) * 16;
      const float* src = Wt + (size_t)(kb * KB + kk) * DIM + j0;
      float4 v0 = *(const float4*)(src + 0);
      float4 v1 = *(const float4*)(src + 4);
      float4 v2 = *(const float4*)(src + 8);
      float4 v3 = *(const float4*)(src + 12);
      *(float4*)&Bs[kk][j0 + 0] = v0;
      *(float4*)&Bs[kk][j0 + 4] = v1;
      *(float4*)&Bs[kk][j0 + 8] = v2;
      *(float4*)&Bs[kk][j0 + 12] = v3;
    }
    __syncthreads();
#pragma unroll
    for (int kk = 0; kk < KB; ++kk) {
      float a[8], b[8];
      *(float4*)&a[0] = *(const float4*)&As[kk][8 * tr];
      *(float4*)&a[4] = *(const float4*)&As[kk][8 * tr + 4];
      *(float4*)&b[0] = *(const float4*)&Bs[kk][8 * tc];
      *(float4*)&b[4] = *(const float4*)&Bs[kk][8 * tc + 4];
#pragma unroll
      for (int i = 0; i < 8; ++i)
#pragma unroll
        for (int j = 0; j < 8; ++j) acc[i][j] += a[i] * b[j];
    }
    __syncthreads();
  }
  // --- epilogue: add bias, store ---
  float bv[8];
#pragma unroll
  for (int j = 0; j < 8; ++j) bv[j] = bl[8 * tc + j];
#pragma unroll
  for (int i = 0; i < 8; ++i) {
    int n = n0 + 8 * tr + i;
    if (n < N_NODES) {
      float o[8];
#pragma unroll
      for (int j = 0; j < 8; ++j) o[j] = acc[i][j] + bv[j];
      float* dst = h + (size_t)n * DIM + 8 * tc;
      *(float4*)(dst + 0) = *(float4*)&o[0];
      *(float4*)(dst + 4) = *(float4*)&o[4];
    }
  }
}

__global__ void k_bn_stats(const float* __restrict__ h, float* __restrict__ sums) {
  int j = threadIdx.x;  // 128 threads = 128 features
  float s = 0.f, q = 0.f;
  for (int n = blockIdx.x; n < N_NODES; n += gridDim.x) {
    float v = h[n * DIM + j];
    s += v;
    q += v * v;
  }
  atomicAdd(&sums[j], s);
  atomicAdd(&sums[DIM + j], q);
}

__global__ void k_bn_apply(const float* __restrict__ h, const float* __restrict__ sums,
                           const float* __restrict__ gamma, const float* __restrict__ beta,
                           float* __restrict__ xout) {
  int i4 = blockIdx.x * blockDim.x + threadIdx.x;
  if (i4 >= N_NODES * DIM / 4) return;
  int j0 = (i4 * 4) & (DIM - 1);
  float4 v = ((const float4*)h)[i4];
  float o[4] = {v.x, v.y, v.z, v.w};
#pragma unroll
  for (int u = 0; u < 4; ++u) {
    int j = j0 + u;
    float mu = sums[j] * (1.0f / N_NODES);
    float var = sums[DIM + j] * (1.0f / N_NODES) - mu * mu;
    float sc = gamma[j] * rsqrtf(var + BN_EPS);
    o[u] = fmaxf((o[u] - mu) * sc + beta[j], 0.f);
  }
  float4 r = {o[0], o[1], o[2], o[3]};
  ((float4*)xout)[i4] = r;
}

// ---------------- pooling + head ----------------

__global__ void k_pool(const float* __restrict__ x, const int* __restrict__ batch,
                       float* __restrict__ pooled, float* __restrict__ gcnt) {
  int i = blockIdx.x * blockDim.x + threadIdx.x;
  if (i >= N_NODES * DIM) return;
  int n = i >> 7, j = i & 127;
  int g = batch[n];
  atomicAdd(&pooled[g * DIM + j], x[i]);
  if (j == 0) atomicAdd(&gcnt[g], 1.0f);
}

__global__ void k_head(const float* __restrict__ pooled, const float* __restrict__ gcnt,
                       const float* __restrict__ W1, const float* __restrict__ b1,
                       const float* __restrict__ W2, const float* __restrict__ b2,
                       float* __restrict__ out) {
  __shared__ float pm[NGRAPHS * DIM];  // 32 KB
  __shared__ float hid[NGRAPHS * 64];  // 16 KB
  for (int i = threadIdx.x; i < NGRAPHS * DIM; i += blockDim.x) {
    int g = i >> 7;
    pm[i] = pooled[i] / fmaxf(gcnt[g], 1.0f);
  }
  __syncthreads();
  for (int i = threadIdx.x; i < NGRAPHS * 64; i += blockDim.x) {
    int g = i >> 6, m = i & 63;
    float acc = b1[m];
    for (int k = 0; k < DIM; ++k) acc += pm[g * DIM + k] * W1[m * DIM + k];
    hid[i] = fmaxf(acc, 0.f);
  }
  __syncthreads();
  for (int i = threadIdx.x; i < NGRAPHS * NCLASSES; i += blockDim.x) {
    int g = i / NCLASSES, c = i % NCLASSES;
    float acc = b2[c];
    for (int m = 0; m < 64; ++m) acc += hid[g * 64 + m] * W2[c * 64 + m];
    out[i] = acc;
  }
}

// ---------------- launch ----------------

extern "C" void kernel_launch(void* const* d_in, const int* in_sizes, int n_in,
                              void* d_out, int out_size, void* d_ws, size_t ws_size,
                              hipStream_t stream) {
  const float* x = (const float*)d_in[0];
  const int* edge = (const int*)d_in[1];
  const int* batch = (const int*)d_in[2];
  const float* Wl = (const float*)d_in[3];
  const float* bl = (const float*)d_in[4];
  const float* Wr = (const float*)d_in[5];
  const float* gamma = (const float*)d_in[6];
  const float* beta = (const float*)d_in[7];
  const float* W1 = (const float*)d_in[8];
  const float* b1 = (const float*)d_in[9];
  const float* W2 = (const float*)d_in[10];
  const float* b2 = (const float*)d_in[11];
  float* out = (float*)d_out;

  const int* src = edge;
  const int* dst = edge + N_EDGES;

  char* p = (char*)d_ws;
  auto alloc = [&](size_t bytes) -> void* {
    void* r = (void*)p;
    p += (bytes + 255) & ~(size_t)255;
    return r;
  };
  int* cnt = (int*)alloc(N_NODES * 4);
  int* incl = (int*)alloc(N_NODES * 4);
  int* bsum = (int*)alloc(SCAN_BLK * 4);
  int* boff = (int*)alloc(SCAN_BLK * 4);
  int* row_ptr = (int*)alloc((N_NODES + 1) * 4);
  int* cursor = (int*)alloc(N_NODES * 4);
  int* col = (int*)alloc(N_EDGES * 4);
  float* degf = (float*)alloc(N_NODES * 4);
  float* Wt = (float*)alloc((size_t)NLAYERS * 2 * DIM * DIM * 4);
  float* x_cur = (float*)alloc((size_t)N_NODES * DIM * 4);
  float* agg = (float*)alloc((size_t)N_NODES * DIM * 4);
  float* hbuf = (float*)alloc((size_t)N_NODES * DIM * 4);
  float* sums = (float*)alloc(2 * DIM * 4);
  float* pooled = (float*)alloc(NGRAPHS * DIM * 4);
  float* gcnt = (float*)alloc(NGRAPHS * 4);

  // ---- CSR build + weight transpose ----
  hipMemsetAsync(cnt, 0, N_NODES * 4, stream);
  k_count<<<(N_EDGES + 255) / 256, 256, 0, stream>>>(dst, cnt);
  k_scan_a<<<SCAN_NB, SCAN_BLK, 0, stream>>>(cnt, incl, bsum);
  k_scan_b<<<1, SCAN_BLK, 0, stream>>>(bsum, boff);
  k_scan_c<<<SCAN_NB, SCAN_BLK, 0, stream>>>(cnt, incl, boff, row_ptr, cursor, degf);
  k_fill<<<(N_EDGES + 255) / 256, 256, 0, stream>>>(src, dst, cursor, col);
  k_wt<<<(NLAYERS * 2 * DIM * DIM + 255) / 256, 256, 0, stream>>>(Wl, Wr, Wt);

  // ---- layers ----
  const float* xin = x;
  for (int l = 0; l < NLAYERS; ++l) {
    k_gather<<<(N_NODES + 3) / 4, 256, 0, stream>>>(xin, row_ptr, col, degf, agg);
    k_gemm2<<<GEMM_NB, 256, 0, stream>>>(agg, xin, Wt + (size_t)l * 2 * DIM * DIM,
                                         bl + (size_t)l * DIM, hbuf);
    hipMemsetAsync(sums, 0, 2 * DIM * 4, stream);
    k_bn_stats<<<512, DIM, 0, stream>>>(hbuf, sums);
    k_bn_apply<<<(N_NODES * DIM / 4 + 255) / 256, 256, 0, stream>>>(
        hbuf, sums, gamma + (size_t)l * DIM, beta + (size_t)l * DIM, x_cur);
    xin = x_cur;
  }

  // ---- pool + head ----
  hipMemsetAsync(pooled, 0, NGRAPHS * DIM * 4, stream);
  hipMemsetAsync(gcnt, 0, NGRAPHS * 4, stream);
  k_pool<<<(N_NODES * DIM) / 256, 256, 0, stream>>>(x_cur, batch, pooled, gcnt);
  k_head<<<1, 256, 0, stream>>>(pooled, gcnt, W1, b1, W2, b2, out);
}

// Round 3
// 688.189 us; speedup vs baseline: 5.4311x; 1.6764x over previous
//
#include <hip/hip_runtime.h>

#define N_NODES 50000
#define N_EDGES 800000
#define DIM 128
#define NLAYERS 3
#define NCLASSES 6
#define NGRAPHS 64
#define BN_EPS 1e-5f

#define SCAN_BLK 256
#define SCAN_NB ((N_NODES + SCAN_BLK - 1) / SCAN_BLK)  // 196

// GEMM tiling
#define TM 128
#define KB 32
#define GEMM_NB ((N_NODES + TM - 1) / TM)  // 391

#define POOL_CHUNKS 8

// ---------------- CSR build ----------------

__global__ void k_count(const int* __restrict__ dst, int* __restrict__ cnt) {
  int e = blockIdx.x * blockDim.x + threadIdx.x;
  if (e < N_EDGES) atomicAdd(&cnt[dst[e]], 1);
}

__global__ void k_scan_a(const int* __restrict__ cnt, int* __restrict__ incl,
                         int* __restrict__ bsum) {
  __shared__ int s[SCAN_BLK];
  int i = blockIdx.x * SCAN_BLK + threadIdx.x;
  int v = (i < N_NODES) ? cnt[i] : 0;
  s[threadIdx.x] = v;
  __syncthreads();
  for (int off = 1; off < SCAN_BLK; off <<= 1) {
    int t = (threadIdx.x >= off) ? s[threadIdx.x - off] : 0;
    __syncthreads();
    s[threadIdx.x] += t;
    __syncthreads();
  }
  if (i < N_NODES) incl[i] = s[threadIdx.x];
  if (threadIdx.x == SCAN_BLK - 1) bsum[blockIdx.x] = s[SCAN_BLK - 1];
}

__global__ void k_scan_b(const int* __restrict__ bsum, int* __restrict__ boff) {
  __shared__ int s[SCAN_BLK];
  int t = threadIdx.x;
  int v = (t < SCAN_NB) ? bsum[t] : 0;
  s[t] = v;
  __syncthreads();
  for (int off = 1; off < SCAN_BLK; off <<= 1) {
    int u = (t >= off) ? s[t - off] : 0;
    __syncthreads();
    s[t] += u;
    __syncthreads();
  }
  boff[t] = s[t] - v;  // exclusive prefix of block sums
}

__global__ void k_scan_c(const int* __restrict__ cnt, const int* __restrict__ incl,
                         const int* __restrict__ boff, int* __restrict__ row_ptr,
                         int* __restrict__ cursor, float* __restrict__ degf) {
  int i = blockIdx.x * SCAN_BLK + threadIdx.x;
  if (i < N_NODES) {
    int ex = incl[i] - cnt[i] + boff[blockIdx.x];
    row_ptr[i] = ex;
    cursor[i] = ex;
    degf[i] = (float)max(cnt[i], 1);
  }
  if (i == 0) row_ptr[N_NODES] = N_EDGES;
}

__global__ void k_fill(const int* __restrict__ src, const int* __restrict__ dst,
                       int* __restrict__ cursor, int* __restrict__ col) {
  int e = blockIdx.x * blockDim.x + threadIdx.x;
  if (e < N_EDGES) {
    int pos = atomicAdd(&cursor[dst[e]], 1);
    col[pos] = src[e];
  }
}

// ---------------- weight pre-transpose ----------------
// Wt[l][k][j]: k<128 -> Wl[l][j][k], k>=128 -> Wr[l][j][k-128]
__global__ void k_wt(const float* __restrict__ Wl, const float* __restrict__ Wr,
                     float* __restrict__ Wt) {
  int i = blockIdx.x * blockDim.x + threadIdx.x;  // over NLAYERS*256*128
  if (i >= NLAYERS * 2 * DIM * DIM) return;
  int j = i & (DIM - 1);
  int k = (i >> 7) & 255;
  int l = i >> 15;
  float v;
  if (k < DIM)
    v = Wl[(size_t)l * DIM * DIM + j * DIM + k];
  else
    v = Wr[(size_t)l * DIM * DIM + j * DIM + (k - DIM)];
  Wt[i] = v;
}

// ---------------- per-layer kernels ----------------

// one wave per node; lane holds 2 features (float2); neighbor loop unrolled x4
// to keep 4 independent 512B row-loads in flight (latency hiding).
__global__ void k_gather(const float* __restrict__ xin, const int* __restrict__ row_ptr,
                         const int* __restrict__ col, const float* __restrict__ degf,
                         float* __restrict__ agg) {
  int wid = threadIdx.x >> 6, lane = threadIdx.x & 63;
  int n = blockIdx.x * 4 + wid;
  if (n >= N_NODES) return;
  int beg = row_ptr[n], end = row_ptr[n + 1];
  const float2* x2 = (const float2*)xin;
  float ax = 0.f, ay = 0.f;
  int p = beg;
  for (; p + 3 < end; p += 4) {
    int c0 = col[p], c1 = col[p + 1], c2 = col[p + 2], c3 = col[p + 3];
    float2 v0 = x2[c0 * 64 + lane];
    float2 v1 = x2[c1 * 64 + lane];
    float2 v2 = x2[c2 * 64 + lane];
    float2 v3 = x2[c3 * 64 + lane];
    ax += v0.x + v1.x + v2.x + v3.x;
    ay += v0.y + v1.y + v2.y + v3.y;
  }
  for (; p < end; ++p) {
    float2 v = x2[col[p] * 64 + lane];
    ax += v.x;
    ay += v.y;
  }
  float inv = 1.0f / degf[n];
  ((float2*)agg)[n * 64 + lane] = make_float2(ax * inv, ay * inv);
}

// Tiled SGEMM: h[n][j] = bl[j] + sum_k [agg|x][n][k] * Wt[k][j]
__global__ __launch_bounds__(256) void k_gemm2(
    const float* __restrict__ agg, const float* __restrict__ xin,
    const float* __restrict__ Wt, const float* __restrict__ bl,
    float* __restrict__ h) {
  __shared__ float As[KB][TM + 1];  // transposed A tile (k-major)
  __shared__ float Bs[KB][DIM];
  int n0 = blockIdx.x * TM;
  int tid = threadIdx.x;
  int tr = tid >> 4;  // 0..15 -> rows 8*tr..
  int tc = tid & 15;  // 0..15 -> cols 8*tc..

  float acc[8][8];
#pragma unroll
  for (int i = 0; i < 8; ++i)
#pragma unroll
    for (int j = 0; j < 8; ++j) acc[i][j] = 0.f;

#pragma unroll 1
  for (int kb = 0; kb < 8; ++kb) {
    const float* Asrc = (kb < 4) ? agg : xin;
    int c0 = (kb & 3) * KB;
#pragma unroll
    for (int p = 0; p < 4; ++p) {
      int r = p * 32 + (tid >> 3);
      int rg = n0 + r;
      if (rg > N_NODES - 1) rg = N_NODES - 1;  // clamp (stores are guarded)
      int c4 = (tid & 7) * 4;
      float4 v = *(const float4*)(Asrc + (size_t)rg * DIM + c0 + c4);
      As[c4 + 0][r] = v.x;
      As[c4 + 1][r] = v.y;
      As[c4 + 2][r] = v.z;
      As[c4 + 3][r] = v.w;
    }
    {
      int kk = tid >> 3;
      int j0 = (tid & 7) * 16;
      const float* src = Wt + (size_t)(kb * KB + kk) * DIM + j0;
      float4 v0 = *(const float4*)(src + 0);
      float4 v1 = *(const float4*)(src + 4);
      float4 v2 = *(const float4*)(src + 8);
      float4 v3 = *(const float4*)(src + 12);
      *(float4*)&Bs[kk][j0 + 0] = v0;
      *(float4*)&Bs[kk][j0 + 4] = v1;
      *(float4*)&Bs[kk][j0 + 8] = v2;
      *(float4*)&Bs[kk][j0 + 12] = v3;
    }
    __syncthreads();
#pragma unroll
    for (int kk = 0; kk < KB; ++kk) {
      float a[8], b[8];
      *(float4*)&a[0] = *(const float4*)&As[kk][8 * tr];
      *(float4*)&a[4] = *(const float4*)&As[kk][8 * tr + 4];
      *(float4*)&b[0] = *(const float4*)&Bs[kk][8 * tc];
      *(float4*)&b[4] = *(const float4*)&Bs[kk][8 * tc + 4];
#pragma unroll
      for (int i = 0; i < 8; ++i)
#pragma unroll
        for (int j = 0; j < 8; ++j) acc[i][j] += a[i] * b[j];
    }
    __syncthreads();
  }
  float bv[8];
#pragma unroll
  for (int j = 0; j < 8; ++j) bv[j] = bl[8 * tc + j];
#pragma unroll
  for (int i = 0; i < 8; ++i) {
    int n = n0 + 8 * tr + i;
    if (n < N_NODES) {
      float o[8];
#pragma unroll
      for (int j = 0; j < 8; ++j) o[j] = acc[i][j] + bv[j];
      float* dst = h + (size_t)n * DIM + 8 * tc;
      *(float4*)(dst + 0) = *(float4*)&o[0];
      *(float4*)(dst + 4) = *(float4*)&o[4];
    }
  }
}

__global__ void k_bn_stats(const float* __restrict__ h, float* __restrict__ sums) {
  int j = threadIdx.x;  // 128 threads = 128 features
  float s = 0.f, q = 0.f;
  for (int n = blockIdx.x; n < N_NODES; n += gridDim.x) {
    float v = h[n * DIM + j];
    s += v;
    q += v * v;
  }
  atomicAdd(&sums[j], s);
  atomicAdd(&sums[DIM + j], q);
}

__global__ void k_bn_apply(const float* __restrict__ h, const float* __restrict__ sums,
                           const float* __restrict__ gamma, const float* __restrict__ beta,
                           float* __restrict__ xout) {
  int i4 = blockIdx.x * blockDim.x + threadIdx.x;
  if (i4 >= N_NODES * DIM / 4) return;
  int j0 = (i4 * 4) & (DIM - 1);
  float4 v = ((const float4*)h)[i4];
  float o[4] = {v.x, v.y, v.z, v.w};
#pragma unroll
  for (int u = 0; u < 4; ++u) {
    int j = j0 + u;
    float mu = sums[j] * (1.0f / N_NODES);
    float var = sums[DIM + j] * (1.0f / N_NODES) - mu * mu;
    float sc = gamma[j] * rsqrtf(var + BN_EPS);
    o[u] = fmaxf((o[u] - mu) * sc + beta[j], 0.f);
  }
  float4 r = {o[0], o[1], o[2], o[3]};
  ((float4*)xout)[i4] = r;
}

// ---------------- pooling + head ----------------

// per-graph row ranges via binary search in the sorted batch array
__global__ void k_gbounds(const int* __restrict__ batch, int* __restrict__ gstart) {
  int t = threadIdx.x;
  if (t > NGRAPHS) return;
  if (t == NGRAPHS) {
    gstart[NGRAPHS] = N_NODES;
    return;
  }
  int lo = 0, hi = N_NODES;
  while (lo < hi) {
    int mid = (lo + hi) >> 1;
    if (batch[mid] < t) lo = mid + 1;
    else hi = mid;
  }
  gstart[t] = lo;
}

// 64 graphs x 8 chunks; each block sums a contiguous row range (coalesced),
// one atomicAdd per feature per block (8-way contention only).
__global__ void k_pool2(const float* __restrict__ x, const int* __restrict__ gstart,
                        float* __restrict__ pooled) {
  int g = blockIdx.x >> 3;
  int ck = blockIdx.x & 7;
  int s = gstart[g], e = gstart[g + 1];
  int len = e - s;
  int per = (len + POOL_CHUNKS - 1) / POOL_CHUNKS;
  int rs = s + ck * per;
  int re = min(rs + per, e);
  int j = threadIdx.x & 127;
  int rg = threadIdx.x >> 7;  // 0..1
  float acc = 0.f;
  for (int r = rs + rg; r < re; r += 2) acc += x[(size_t)r * DIM + j];
  __shared__ float sred[2][DIM];
  sred[rg][j] = acc;
  __syncthreads();
  if (rg == 0) {
    float v = sred[0][j] + sred[1][j];
    atomicAdd(&pooled[g * DIM + j], v);
  }
}

__global__ void k_head(const float* __restrict__ pooled, const int* __restrict__ gstart,
                       const float* __restrict__ W1, const float* __restrict__ b1,
                       const float* __restrict__ W2, const float* __restrict__ b2,
                       float* __restrict__ out) {
  __shared__ float pm[NGRAPHS * DIM];  // 32 KB
  __shared__ float hid[NGRAPHS * 64];  // 16 KB
  for (int i = threadIdx.x; i < NGRAPHS * DIM; i += blockDim.x) {
    int g = i >> 7;
    float c = (float)(gstart[g + 1] - gstart[g]);
    pm[i] = pooled[i] / fmaxf(c, 1.0f);
  }
  __syncthreads();
  for (int i = threadIdx.x; i < NGRAPHS * 64; i += blockDim.x) {
    int g = i >> 6, m = i & 63;
    float acc = b1[m];
    for (int k = 0; k < DIM; ++k) acc += pm[g * DIM + k] * W1[m * DIM + k];
    hid[i] = fmaxf(acc, 0.f);
  }
  __syncthreads();
  for (int i = threadIdx.x; i < NGRAPHS * NCLASSES; i += blockDim.x) {
    int g = i / NCLASSES, c = i % NCLASSES;
    float acc = b2[c];
    for (int m = 0; m < 64; ++m) acc += hid[g * 64 + m] * W2[c * 64 + m];
    out[i] = acc;
  }
}

// ---------------- launch ----------------

extern "C" void kernel_launch(void* const* d_in, const int* in_sizes, int n_in,
                              void* d_out, int out_size, void* d_ws, size_t ws_size,
                              hipStream_t stream) {
  const float* x = (const float*)d_in[0];
  const int* edge = (const int*)d_in[1];
  const int* batch = (const int*)d_in[2];
  const float* Wl = (const float*)d_in[3];
  const float* bl = (const float*)d_in[4];
  const float* Wr = (const float*)d_in[5];
  const float* gamma = (const float*)d_in[6];
  const float* beta = (const float*)d_in[7];
  const float* W1 = (const float*)d_in[8];
  const float* b1 = (const float*)d_in[9];
  const float* W2 = (const float*)d_in[10];
  const float* b2 = (const float*)d_in[11];
  float* out = (float*)d_out;

  const int* src = edge;
  const int* dst = edge + N_EDGES;

  char* p = (char*)d_ws;
  auto alloc = [&](size_t bytes) -> void* {
    void* r = (void*)p;
    p += (bytes + 255) & ~(size_t)255;
    return r;
  };
  int* cnt = (int*)alloc(N_NODES * 4);
  int* incl = (int*)alloc(N_NODES * 4);
  int* bsum = (int*)alloc(SCAN_BLK * 4);
  int* boff = (int*)alloc(SCAN_BLK * 4);
  int* row_ptr = (int*)alloc((N_NODES + 1) * 4);
  int* cursor = (int*)alloc(N_NODES * 4);
  int* col = (int*)alloc(N_EDGES * 4);
  float* degf = (float*)alloc(N_NODES * 4);
  float* Wt = (float*)alloc((size_t)NLAYERS * 2 * DIM * DIM * 4);
  float* x_cur = (float*)alloc((size_t)N_NODES * DIM * 4);
  float* agg = (float*)alloc((size_t)N_NODES * DIM * 4);
  float* hbuf = (float*)alloc((size_t)N_NODES * DIM * 4);
  float* sums = (float*)alloc(2 * DIM * 4);
  float* pooled = (float*)alloc(NGRAPHS * DIM * 4);
  int* gstart = (int*)alloc((NGRAPHS + 1) * 4);

  // ---- CSR build + weight transpose + graph bounds ----
  hipMemsetAsync(cnt, 0, N_NODES * 4, stream);
  k_count<<<(N_EDGES + 255) / 256, 256, 0, stream>>>(dst, cnt);
  k_scan_a<<<SCAN_NB, SCAN_BLK, 0, stream>>>(cnt, incl, bsum);
  k_scan_b<<<1, SCAN_BLK, 0, stream>>>(bsum, boff);
  k_scan_c<<<SCAN_NB, SCAN_BLK, 0, stream>>>(cnt, incl, boff, row_ptr, cursor, degf);
  k_fill<<<(N_EDGES + 255) / 256, 256, 0, stream>>>(src, dst, cursor, col);
  k_wt<<<(NLAYERS * 2 * DIM * DIM + 255) / 256, 256, 0, stream>>>(Wl, Wr, Wt);
  k_gbounds<<<1, 128, 0, stream>>>(batch, gstart);

  // ---- layers ----
  const float* xin = x;
  for (int l = 0; l < NLAYERS; ++l) {
    k_gather<<<(N_NODES + 3) / 4, 256, 0, stream>>>(xin, row_ptr, col, degf, agg);
    k_gemm2<<<GEMM_NB, 256, 0, stream>>>(agg, xin, Wt + (size_t)l * 2 * DIM * DIM,
                                         bl + (size_t)l * DIM, hbuf);
    hipMemsetAsync(sums, 0, 2 * DIM * 4, stream);
    k_bn_stats<<<512, DIM, 0, stream>>>(hbuf, sums);
    k_bn_apply<<<(N_NODES * DIM / 4 + 255) / 256, 256, 0, stream>>>(
        hbuf, sums, gamma + (size_t)l * DIM, beta + (size_t)l * DIM, x_cur);
    xin = x_cur;
  }

  // ---- pool + head ----
  hipMemsetAsync(pooled, 0, NGRAPHS * DIM * 4, stream);
  k_pool2<<<NGRAPHS * POOL_CHUNKS, 256, 0, stream>>>(x_cur, gstart, pooled);
  k_head<<<1, 256, 0, stream>>>(pooled, gstart, W1, b1, W2, b2, out);
}